// Round 1
// baseline (1160.911 us; speedup 1.0000x reference)
//
#include <hip/hip_runtime.h>

typedef __attribute__((ext_vector_type(8))) short short8;
typedef __attribute__((ext_vector_type(4))) float floatx4;

// f32 -> bf16 round-to-nearest-even (inputs are finite; no NaN guard needed)
__device__ __forceinline__ short f2bf(float f) {
    unsigned int u = __float_as_uint(f);
    u = (u + 0x7FFFu + ((u >> 16) & 1u)) >> 16;
    return (short)u;
}

// ---------------- CSR build ----------------

__global__ void zero_i32(int* __restrict__ p, int n) {
    int i = blockIdx.x * blockDim.x + threadIdx.x;
    if (i < n) p[i] = 0;
}

__global__ void count_deg(const int* __restrict__ dst, int* __restrict__ cnt, int E) {
    int e = blockIdx.x * blockDim.x + threadIdx.x;
    if (e < E) atomicAdd(&cnt[dst[e]], 1);
}

// per-1024-chunk sums (256 threads x 4 elems)
__global__ void scan_part(const int* __restrict__ cnt, int* __restrict__ bsums, int N) {
    __shared__ int sh[256];
    int tid = threadIdx.x;
    int base = blockIdx.x * 1024 + tid * 4;
    int s = 0;
#pragma unroll
    for (int j = 0; j < 4; ++j) { int idx = base + j; if (idx < N) s += cnt[idx]; }
    sh[tid] = s; __syncthreads();
    for (int d = 128; d > 0; d >>= 1) { if (tid < d) sh[tid] += sh[tid + d]; __syncthreads(); }
    if (tid == 0) bsums[blockIdx.x] = sh[0];
}

// exclusive scan of up to 1024 block sums, single block of 1024 threads
__global__ void scan_small(int* __restrict__ b, int nb) {
    __shared__ int s[1024];
    int tid = threadIdx.x;
    int v = (tid < nb) ? b[tid] : 0;
    s[tid] = v; __syncthreads();
    for (int d = 1; d < 1024; d <<= 1) {
        int t = (tid >= d) ? s[tid - d] : 0;
        __syncthreads();
        s[tid] += t;
        __syncthreads();
    }
    if (tid < nb) b[tid] = s[tid] - v;
}

__global__ void scan_final(const int* __restrict__ cnt, const int* __restrict__ bsums,
                           int* __restrict__ off,
                           float* __restrict__ dinv, int N) {
    __shared__ int sh[256];
    int tid = threadIdx.x;
    int base = blockIdx.x * 1024 + tid * 4;
    int v[4]; int tsum = 0;
#pragma unroll
    for (int j = 0; j < 4; ++j) { int idx = base + j; v[j] = (idx < N) ? cnt[idx] : 0; tsum += v[j]; }
    sh[tid] = tsum; __syncthreads();
    for (int d = 1; d < 256; d <<= 1) {
        int t = (tid >= d) ? sh[tid - d] : 0;
        __syncthreads();
        sh[tid] += t;
        __syncthreads();
    }
    int run = sh[tid] - tsum + bsums[blockIdx.x];
#pragma unroll
    for (int j = 0; j < 4; ++j) {
        int idx = base + j;
        if (idx < N) {
            off[idx] = run;
            dinv[idx] = rsqrtf((float)(v[j] + 1));   // deg includes self-loop
            run += v[j];
        }
    }
}

// bucket cursors: bucket b = nodes [b*64, (b+1)*64); cursor starts at off[b*64]
__global__ void init_bcur(const int* __restrict__ off, int* __restrict__ bcur, int NB) {
    int b = blockIdx.x * blockDim.x + threadIdx.x;
    if (b < NB) bcur[b] = off[b << 6];
}

// Phase A: bin edges by dst>>6 into the FINAL edges array (bucket ranges == CSR
// bucket ranges). Write frontier = ~1563 lines (L2-resident) -> dense writebacks.
__global__ void bin_edges(const int* __restrict__ eidx, int* __restrict__ bcur,
                          int2* __restrict__ edges, int E) {
    int e = blockIdx.x * blockDim.x + threadIdx.x;
    if (e >= E) return;
    int s = eidx[e];        // src
    int d = eidx[E + e];    // dst
    int p = atomicAdd(&bcur[d >> 6], 1);
    edges[p] = make_int2(s, d);
}

// Phase B: one block per bucket. Stage bucket in LDS, then scatter in-place to
// per-node CSR slots using LDS atomics on 64 local cursors. Converts (s,d)->(s,norm).
#define BUCKET_CAP 6144   // mean 2048, sigma ~45 for uniform dst -> 90-sigma margin
__global__ __launch_bounds__(256) void perm_edges(const int* __restrict__ off,
                                                  const float* __restrict__ dinv,
                                                  int2* __restrict__ edges,
                                                  int N, int E) {
    __shared__ int2 sh[BUCKET_CAP];      // 48 KB
    __shared__ int curs[64];
    int b = blockIdx.x;
    int n0 = b << 6;
    int n1 = n0 + 64; if (n1 > N) n1 = N;
    int p0 = off[n0];
    int p1 = (n1 < N) ? off[n1] : E;
    int cnt = p1 - p0;
    if (cnt > BUCKET_CAP) cnt = BUCKET_CAP;   // unreachable for this input; avoid OOB
    int tid = threadIdx.x;
    if (tid < 64) {
        int nn = n0 + tid;
        curs[tid] = (nn < N) ? (off[nn] - p0) : 0;   // local offset within bucket
    }
    for (int i = tid; i < cnt; i += 256) sh[i] = edges[p0 + i];
    __syncthreads();
    for (int i = tid; i < cnt; i += 256) {
        int2 t = sh[i];
        float nm = dinv[t.x] * dinv[t.y];
        int p = atomicAdd(&curs[t.y & 63], 1);       // LDS atomic, bucket-local
        edges[p0 + p] = make_int2(t.x, __float_as_int(nm));
    }
}

// ---------------- layer 1 GEMM: h1[N,16] = x[N,512] @ W1[512,16] ----------------
// wave = one 16x16 output tile, mfma_f32_16x16x32_bf16, f32 inputs cvt'd to bf16 in-register.
__global__ __launch_bounds__(256) void gemm1_mfma(const float* __restrict__ x,
                                                  const float* __restrict__ w1,
                                                  float* __restrict__ h1,
                                                  int ntiles, int N) {
    __shared__ __align__(16) float wl[512 * 16];    // 32 KB
    int tid = threadIdx.x;
    for (int i = tid; i < 2048; i += 256)           // 8192 floats = 2048 float4
        ((float4*)wl)[i] = ((const float4*)w1)[i];
    __syncthreads();

    int lane = tid & 63;
    int q = lane >> 4, r = lane & 15;

    // B fragments for all 16 K-iters: lane holds B[k=q*8+j][n=r]
    short8 bf[16];
#pragma unroll
    for (int kk = 0; kk < 16; ++kk) {
        int kb = kk * 32 + q * 8;
        short8 t;
#pragma unroll
        for (int j = 0; j < 8; ++j) t[j] = f2bf(wl[(kb + j) * 16 + r]);
        bf[kk] = t;
    }

    int tile = blockIdx.x * 4 + (tid >> 6);
    if (tile >= ntiles) return;
    int nb = tile * 16;
    int row = nb + r; if (row >= N) row = N - 1;
    const float* xp = x + (size_t)row * 512 + q * 8;   // A[m=r][k=q*8+j]
    floatx4 acc = {0.f, 0.f, 0.f, 0.f};
#pragma unroll
    for (int kk = 0; kk < 16; ++kk) {
        float4 a0 = *(const float4*)(xp + kk * 32);
        float4 a1 = *(const float4*)(xp + kk * 32 + 4);
        short8 af;
        af[0] = f2bf(a0.x); af[1] = f2bf(a0.y); af[2] = f2bf(a0.z); af[3] = f2bf(a0.w);
        af[4] = f2bf(a1.x); af[5] = f2bf(a1.y); af[6] = f2bf(a1.z); af[7] = f2bf(a1.w);
        acc = __builtin_amdgcn_mfma_f32_16x16x32_bf16(af, bf[kk], acc, 0, 0, 0);
    }
    // C/D: col=lane&15, row=(lane>>4)*4+i
#pragma unroll
    for (int i = 0; i < 4; ++i) {
        int rr = nb + q * 4 + i;
        if (rr < N) h1[(size_t)rr * 16 + r] = acc[i];
    }
}

// ---------------- CSR aggregate over 16-dim features ----------------
// full wave per node: lane = h (feature, bits 0..3) x j (edge slot, bits 4..5).
// 4-way edge ILP shortens the dependent load->gather chain; shfl_xor reduce over j.
__global__ __launch_bounds__(256) void agg16w(const float* __restrict__ in, float* __restrict__ out,
                                              const int* __restrict__ off, const int* __restrict__ cnt,
                                              const float* __restrict__ dinv, const int2* __restrict__ edges,
                                              const float* __restrict__ bias, int relu, int N) {
    int t = blockIdx.x * blockDim.x + threadIdx.x;
    int n = t >> 6;
    if (n >= N) return;
    int lane = t & 63;
    int h = lane & 15, j = lane >> 4;
    int p0 = off[n], c = cnt[n];
    const int2* ep = edges + p0;
    float acc = 0.0f;
    for (int i = j; i < c; i += 4) {
        int2 e = ep[i];
        acc += __int_as_float(e.y) * in[e.x * 16 + h];
    }
    acc += __shfl_xor(acc, 16, 64);
    acc += __shfl_xor(acc, 32, 64);
    if (j == 0) {
        float di = dinv[n];
        float v = acc + di * di * in[n * 16 + h];
        if (bias) v += bias[h];
        if (relu) v = fmaxf(v, 0.0f);
        out[n * 16 + h] = v;
    }
}

// ---------------- fused W2 + bias + log_softmax + f32 store ----------------
// one wave per node; lanes 0..39 = classes
__global__ __launch_bounds__(256) void out_ls(const float* __restrict__ a2,
                                              const float* __restrict__ w2,
                                              const float* __restrict__ b2,
                                              float* __restrict__ out, int N) {
    __shared__ float w2s[704];   // 640 used + zero pad so lanes 40..63 read zeros
    __shared__ float b2s[40];
    int tid = threadIdx.x;
    for (int i = tid; i < 704; i += 256) w2s[i] = (i < 640) ? w2[i] : 0.0f;
    if (tid < 40) b2s[tid] = b2[tid];
    __syncthreads();
    int lane = tid & 63;
    int n = blockIdx.x * 4 + (tid >> 6);
    if (n >= N) return;
    const float* ar = a2 + (size_t)n * 16;
    bool act = lane < 40;
    float acc = act ? b2s[lane] : 0.0f;
#pragma unroll
    for (int k = 0; k < 16; ++k) {
        float av = ar[k];                 // wave-uniform broadcast load
        acc += av * w2s[k * 40 + lane];   // zeros for lanes>=40, discarded below
    }
    float v = act ? acc : -__builtin_inff();
#pragma unroll
    for (int s = 32; s > 0; s >>= 1) v = fmaxf(v, __shfl_xor(v, s, 64));
    float ex = act ? expf(acc - v) : 0.0f;
    float ssum = ex;
#pragma unroll
    for (int s = 32; s > 0; s >>= 1) ssum += __shfl_xor(ssum, s, 64);
    float lse = logf(ssum);
    if (act) out[(size_t)n * 40 + lane] = acc - v - lse;
}

// ---------------- launch ----------------

extern "C" void kernel_launch(void* const* d_in, const int* in_sizes, int n_in,
                              void* d_out, int out_size, void* d_ws, size_t ws_size,
                              hipStream_t stream) {
    const float* x   = (const float*)d_in[0];
    const float* W1  = (const float*)d_in[1];
    const float* b1  = (const float*)d_in[2];
    const float* W2  = (const float*)d_in[3];
    const float* b2  = (const float*)d_in[4];
    const int*   eidx = (const int*)d_in[5];
    float* out = (float*)d_out;

    const int N = in_sizes[0] / 512;
    const int E = in_sizes[5] / 2;

    char* w = (char*)d_ws;
    auto alloc = [&](size_t bytes) { char* p = w; w += (bytes + 255) & ~(size_t)255; return p; };
    int*   cnt   = (int*)alloc((size_t)N * 4);
    int*   off   = (int*)alloc((size_t)N * 4);
    float* dinv  = (float*)alloc((size_t)N * 4);
    int*   bsums = (int*)alloc(1024 * 4);
    int    NB    = (N + 63) / 64;
    int*   bcur  = (int*)alloc((size_t)NB * 4);
    int2*  edges = (int2*)alloc((size_t)E * 8);
    float* h1    = (float*)alloc((size_t)N * 16 * 4);
    float* r1    = (float*)alloc((size_t)N * 16 * 4);
    float* a2    = h1;   // reuse: h1 dead after first agg

    int nb = (N + 1023) / 1024;

    zero_i32<<<(N + 255) / 256, 256, 0, stream>>>(cnt, N);
    count_deg<<<(E + 255) / 256, 256, 0, stream>>>(eidx + E, cnt, E);
    scan_part<<<nb, 256, 0, stream>>>(cnt, bsums, N);
    scan_small<<<1, 1024, 0, stream>>>(bsums, nb);
    scan_final<<<nb, 256, 0, stream>>>(cnt, bsums, off, dinv, N);
    init_bcur<<<(NB + 255) / 256, 256, 0, stream>>>(off, bcur, NB);
    bin_edges<<<(E + 255) / 256, 256, 0, stream>>>(eidx, bcur, edges, E);
    perm_edges<<<NB, 256, 0, stream>>>(off, dinv, edges, N, E);

    int ntiles = (N + 15) / 16;
    gemm1_mfma<<<(ntiles + 3) / 4, 256, 0, stream>>>(x, W1, h1, ntiles, N);

    agg16w<<<((size_t)N * 64 + 255) / 256, 256, 0, stream>>>(h1, r1, off, cnt, dinv, edges, b1, 1, N);
    agg16w<<<((size_t)N * 64 + 255) / 256, 256, 0, stream>>>(r1, a2, off, cnt, dinv, edges, (const float*)nullptr, 0, N);

    out_ls<<<(N + 3) / 4, 256, 0, stream>>>(a2, W2, b2, out, N);
}

// Round 2
// 767.872 us; speedup vs baseline: 1.5119x; 1.5119x over previous
//
#include <hip/hip_runtime.h>

typedef __attribute__((ext_vector_type(8))) short short8;
typedef __attribute__((ext_vector_type(4))) float floatx4;

#define CHUNK 8192   // edges per binning block
#define SHIFT 8      // nodes per bucket = 256

// f32 -> bf16 round-to-nearest-even (inputs are finite; no NaN guard needed)
__device__ __forceinline__ short f2bf(float f) {
    unsigned int u = __float_as_uint(f);
    u = (u + 0x7FFFu + ((u >> 16) & 1u)) >> 16;
    return (short)u;
}

// ---------------- CSR build ----------------

__global__ void zero_i32(int* __restrict__ p, int n) {
    int i = blockIdx.x * blockDim.x + threadIdx.x;
    if (i < n) p[i] = 0;
}

__global__ void count_deg(const int* __restrict__ dst, int* __restrict__ cnt, int E) {
    int e = blockIdx.x * blockDim.x + threadIdx.x;
    if (e < E) atomicAdd(&cnt[dst[e]], 1);
}

// per-1024-chunk sums (256 threads x 4 elems)
__global__ void scan_part(const int* __restrict__ cnt, int* __restrict__ bsums, int N) {
    __shared__ int sh[256];
    int tid = threadIdx.x;
    int base = blockIdx.x * 1024 + tid * 4;
    int s = 0;
#pragma unroll
    for (int j = 0; j < 4; ++j) { int idx = base + j; if (idx < N) s += cnt[idx]; }
    sh[tid] = s; __syncthreads();
    for (int d = 128; d > 0; d >>= 1) { if (tid < d) sh[tid] += sh[tid + d]; __syncthreads(); }
    if (tid == 0) bsums[blockIdx.x] = sh[0];
}

// exclusive scan of up to 1024 block sums, single block of 1024 threads
__global__ void scan_small(int* __restrict__ b, int nb) {
    __shared__ int s[1024];
    int tid = threadIdx.x;
    int v = (tid < nb) ? b[tid] : 0;
    s[tid] = v; __syncthreads();
    for (int d = 1; d < 1024; d <<= 1) {
        int t = (tid >= d) ? s[tid - d] : 0;
        __syncthreads();
        s[tid] += t;
        __syncthreads();
    }
    if (tid < nb) b[tid] = s[tid] - v;
}

__global__ void scan_final(const int* __restrict__ cnt, const int* __restrict__ bsums,
                           int* __restrict__ off,
                           float* __restrict__ dinv, int N) {
    __shared__ int sh[256];
    int tid = threadIdx.x;
    int base = blockIdx.x * 1024 + tid * 4;
    int v[4]; int tsum = 0;
#pragma unroll
    for (int j = 0; j < 4; ++j) { int idx = base + j; v[j] = (idx < N) ? cnt[idx] : 0; tsum += v[j]; }
    sh[tid] = tsum; __syncthreads();
    for (int d = 1; d < 256; d <<= 1) {
        int t = (tid >= d) ? sh[tid - d] : 0;
        __syncthreads();
        sh[tid] += t;
        __syncthreads();
    }
    int run = sh[tid] - tsum + bsums[blockIdx.x];
#pragma unroll
    for (int j = 0; j < 4; ++j) {
        int idx = base + j;
        if (idx < N) {
            off[idx] = run;
            dinv[idx] = rsqrtf((float)(v[j] + 1));   // deg includes self-loop
            run += v[j];
        }
    }
}

// generic exclusive scan, pass 3: apply local scan + block base, in place
__global__ __launch_bounds__(256) void scan_apply(int* __restrict__ v, const int* __restrict__ bsums, int M) {
    __shared__ int sh[256];
    int tid = threadIdx.x;
    int base = blockIdx.x * 1024 + tid * 4;
    int x[4]; int tsum = 0;
#pragma unroll
    for (int j = 0; j < 4; ++j) { int idx = base + j; x[j] = (idx < M) ? v[idx] : 0; tsum += x[j]; }
    sh[tid] = tsum; __syncthreads();
    for (int d = 1; d < 256; d <<= 1) {
        int t = (tid >= d) ? sh[tid - d] : 0;
        __syncthreads();
        sh[tid] += t;
        __syncthreads();
    }
    int run = sh[tid] - tsum + bsums[blockIdx.x];
#pragma unroll
    for (int j = 0; j < 4; ++j) {
        int idx = base + j;
        if (idx < M) { v[idx] = run; run += x[j]; }
    }
}

// Counting-sort pass 1: per-block bucket histogram (bucket = dst>>SHIFT).
// ghist layout is bucket-major [buk][blk] so the exclusive scan yields
// deterministic per-(bucket,block) bases with bucket base == off[buk<<SHIFT].
__global__ __launch_bounds__(256) void blockhist(const int* __restrict__ dst, int* __restrict__ ghist,
                                                 int E, int nbuk, int nblk) {
    __shared__ int lh[512];
    int tid = threadIdx.x, blk = blockIdx.x;
    for (int i = tid; i < nbuk; i += 256) lh[i] = 0;
    __syncthreads();
    int base = blk * CHUNK;
    int end = base + CHUNK; if (end > E) end = E;
    for (int i = base + tid; i < end; i += 256)
        atomicAdd(&lh[dst[i] >> SHIFT], 1);
    __syncthreads();
    for (int i = tid; i < nbuk; i += 256) ghist[(size_t)i * nblk + blk] = lh[i];
}

// Counting-sort pass 2: place edges at deterministic (bucket,block) ranges.
// No global atomics; LDS atomics only for within-block rank. Each bucket-run
// (avg 21 edges, contiguous, block-private) -> dense line writes.
__global__ __launch_bounds__(256) void binpass(const int* __restrict__ eidx, const int* __restrict__ ghist,
                                               int2* __restrict__ ebin, int E, int nbuk, int nblk) {
    __shared__ int lh[512];
    __shared__ int lb[512];
    int tid = threadIdx.x, blk = blockIdx.x;
    for (int i = tid; i < nbuk; i += 256) { lh[i] = 0; lb[i] = ghist[(size_t)i * nblk + blk]; }
    __syncthreads();
    int base = blk * CHUNK;
    int end = base + CHUNK; if (end > E) end = E;
    for (int i = base + tid; i < end; i += 256) {
        int s = eidx[i];
        int d = eidx[E + i];
        int buk = d >> SHIFT;
        int r = atomicAdd(&lh[buk], 1);
        ebin[lb[buk] + r] = make_int2(s, d);
    }
}

// Pass 3: one block per bucket; scatter to per-node CSR slots via 256 LDS
// cursors. All writes land in this block's own ~65KB region -> single-XCD L2
// residency -> dense writeback. Also converts (src,dst)->(src,norm).
__global__ __launch_bounds__(256) void permB(const int* __restrict__ off, const float* __restrict__ dinv,
                                             const int2* __restrict__ ebin, int2* __restrict__ efin,
                                             int N, int E) {
    __shared__ int curs[256];
    int k = blockIdx.x, tid = threadIdx.x;
    int n0 = k << SHIFT;
    int n1 = n0 + 256; if (n1 > N) n1 = N;
    if (tid < n1 - n0) curs[tid] = off[n0 + tid];
    int bstart = off[n0];
    int bend = (n1 < N) ? off[n1] : E;
    __syncthreads();
    for (int i = bstart + tid; i < bend; i += 256) {
        int2 e = ebin[i];
        float nm = dinv[e.x] * dinv[e.y];
        int p = atomicAdd(&curs[e.y & 255], 1);
        efin[p] = make_int2(e.x, __float_as_int(nm));
    }
}

// ---------------- layer 1 GEMM: h1[N,16] = x[N,512] @ W1[512,16] ----------------
// wave = one 16x16 output tile, mfma_f32_16x16x32_bf16, f32 inputs cvt'd to bf16 in-register.
__global__ __launch_bounds__(256) void gemm1_mfma(const float* __restrict__ x,
                                                  const float* __restrict__ w1,
                                                  float* __restrict__ h1,
                                                  int ntiles, int N) {
    __shared__ __align__(16) float wl[512 * 16];    // 32 KB
    int tid = threadIdx.x;
    for (int i = tid; i < 2048; i += 256)           // 8192 floats = 2048 float4
        ((float4*)wl)[i] = ((const float4*)w1)[i];
    __syncthreads();

    int lane = tid & 63;
    int q = lane >> 4, r = lane & 15;

    // B fragments for all 16 K-iters: lane holds B[k=q*8+j][n=r]
    short8 bf[16];
#pragma unroll
    for (int kk = 0; kk < 16; ++kk) {
        int kb = kk * 32 + q * 8;
        short8 t;
#pragma unroll
        for (int j = 0; j < 8; ++j) t[j] = f2bf(wl[(kb + j) * 16 + r]);
        bf[kk] = t;
    }

    int tile = blockIdx.x * 4 + (tid >> 6);
    if (tile >= ntiles) return;
    int nb = tile * 16;
    int row = nb + r; if (row >= N) row = N - 1;
    const float* xp = x + (size_t)row * 512 + q * 8;   // A[m=r][k=q*8+j]
    floatx4 acc = {0.f, 0.f, 0.f, 0.f};
#pragma unroll
    for (int kk = 0; kk < 16; ++kk) {
        float4 a0 = *(const float4*)(xp + kk * 32);
        float4 a1 = *(const float4*)(xp + kk * 32 + 4);
        short8 af;
        af[0] = f2bf(a0.x); af[1] = f2bf(a0.y); af[2] = f2bf(a0.z); af[3] = f2bf(a0.w);
        af[4] = f2bf(a1.x); af[5] = f2bf(a1.y); af[6] = f2bf(a1.z); af[7] = f2bf(a1.w);
        acc = __builtin_amdgcn_mfma_f32_16x16x32_bf16(af, bf[kk], acc, 0, 0, 0);
    }
    // C/D: col=lane&15, row=(lane>>4)*4+i
#pragma unroll
    for (int i = 0; i < 4; ++i) {
        int rr = nb + q * 4 + i;
        if (rr < N) h1[(size_t)rr * 16 + r] = acc[i];
    }
}

// ---------------- CSR aggregate over 16-dim features ----------------
// full wave per node: lane = h (feature, bits 0..3) x j (edge slot, bits 4..5).
// 4-way edge ILP shortens the dependent load->gather chain; shfl_xor reduce over j.
__global__ __launch_bounds__(256) void agg16w(const float* __restrict__ in, float* __restrict__ out,
                                              const int* __restrict__ off, const int* __restrict__ cnt,
                                              const float* __restrict__ dinv, const int2* __restrict__ edges,
                                              const float* __restrict__ bias, int relu, int N) {
    int t = blockIdx.x * blockDim.x + threadIdx.x;
    int n = t >> 6;
    if (n >= N) return;
    int lane = t & 63;
    int h = lane & 15, j = lane >> 4;
    int p0 = off[n], c = cnt[n];
    const int2* ep = edges + p0;
    float acc = 0.0f;
    for (int i = j; i < c; i += 4) {
        int2 e = ep[i];
        acc += __int_as_float(e.y) * in[e.x * 16 + h];
    }
    acc += __shfl_xor(acc, 16, 64);
    acc += __shfl_xor(acc, 32, 64);
    if (j == 0) {
        float di = dinv[n];
        float v = acc + di * di * in[n * 16 + h];
        if (bias) v += bias[h];
        if (relu) v = fmaxf(v, 0.0f);
        out[n * 16 + h] = v;
    }
}

// ---------------- fused W2 + bias + log_softmax + f32 store ----------------
// one wave per node; lanes 0..39 = classes
__global__ __launch_bounds__(256) void out_ls(const float* __restrict__ a2,
                                              const float* __restrict__ w2,
                                              const float* __restrict__ b2,
                                              float* __restrict__ out, int N) {
    __shared__ float w2s[704];   // 640 used + zero pad so lanes 40..63 read zeros
    __shared__ float b2s[40];
    int tid = threadIdx.x;
    for (int i = tid; i < 704; i += 256) w2s[i] = (i < 640) ? w2[i] : 0.0f;
    if (tid < 40) b2s[tid] = b2[tid];
    __syncthreads();
    int lane = tid & 63;
    int n = blockIdx.x * 4 + (tid >> 6);
    if (n >= N) return;
    const float* ar = a2 + (size_t)n * 16;
    bool act = lane < 40;
    float acc = act ? b2s[lane] : 0.0f;
#pragma unroll
    for (int k = 0; k < 16; ++k) {
        float av = ar[k];                 // wave-uniform broadcast load
        acc += av * w2s[k * 40 + lane];   // zeros for lanes>=40, discarded below
    }
    float v = act ? acc : -__builtin_inff();
#pragma unroll
    for (int s = 32; s > 0; s >>= 1) v = fmaxf(v, __shfl_xor(v, s, 64));
    float ex = act ? expf(acc - v) : 0.0f;
    float ssum = ex;
#pragma unroll
    for (int s = 32; s > 0; s >>= 1) ssum += __shfl_xor(ssum, s, 64);
    float lse = logf(ssum);
    if (act) out[(size_t)n * 40 + lane] = acc - v - lse;
}

// ---------------- launch ----------------

extern "C" void kernel_launch(void* const* d_in, const int* in_sizes, int n_in,
                              void* d_out, int out_size, void* d_ws, size_t ws_size,
                              hipStream_t stream) {
    const float* x   = (const float*)d_in[0];
    const float* W1  = (const float*)d_in[1];
    const float* b1  = (const float*)d_in[2];
    const float* W2  = (const float*)d_in[3];
    const float* b2  = (const float*)d_in[4];
    const int*   eidx = (const int*)d_in[5];
    float* out = (float*)d_out;

    const int N = in_sizes[0] / 512;
    const int E = in_sizes[5] / 2;

    const int NBUK = (N + 255) >> SHIFT;          // buckets of 256 nodes
    const int nblk = (E + CHUNK - 1) / CHUNK;     // binning blocks
    const int M = NBUK * nblk;                    // histogram matrix size

    char* w = (char*)d_ws;
    auto alloc = [&](size_t bytes) { char* p = w; w += (bytes + 255) & ~(size_t)255; return p; };
    int*   cnt   = (int*)alloc((size_t)N * 4);
    int*   off   = (int*)alloc((size_t)N * 4);
    float* dinv  = (float*)alloc((size_t)N * 4);
    int*   bsums = (int*)alloc(1024 * 4);
    int*   ghist = (int*)alloc((size_t)M * 4);
    int2*  ebin  = (int2*)alloc((size_t)E * 8);
    int2*  efin  = (int2*)alloc((size_t)E * 8);
    // ebin is dead after permB; reuse its space for h1/r1 (12.8 MB < 25.6 MB)
    float* h1    = (float*)ebin;
    float* r1    = h1 + (size_t)N * 16;
    float* a2    = h1;   // h1 dead after first agg

    int nb = (N + 1023) / 1024;
    int mb = (M + 1023) / 1024;

    zero_i32<<<(N + 255) / 256, 256, 0, stream>>>(cnt, N);
    count_deg<<<(E + 255) / 256, 256, 0, stream>>>(eidx + E, cnt, E);
    scan_part<<<nb, 256, 0, stream>>>(cnt, bsums, N);
    scan_small<<<1, 1024, 0, stream>>>(bsums, nb);
    scan_final<<<nb, 256, 0, stream>>>(cnt, bsums, off, dinv, N);

    blockhist<<<nblk, 256, 0, stream>>>(eidx + E, ghist, E, NBUK, nblk);
    scan_part<<<mb, 256, 0, stream>>>(ghist, bsums, M);
    scan_small<<<1, 1024, 0, stream>>>(bsums, mb);
    scan_apply<<<mb, 256, 0, stream>>>(ghist, bsums, M);
    binpass<<<nblk, 256, 0, stream>>>(eidx, ghist, ebin, E, NBUK, nblk);
    permB<<<NBUK, 256, 0, stream>>>(off, dinv, ebin, efin, N, E);

    int ntiles = (N + 15) / 16;
    gemm1_mfma<<<(ntiles + 3) / 4, 256, 0, stream>>>(x, W1, h1, ntiles, N);

    agg16w<<<((size_t)N * 64 + 255) / 256, 256, 0, stream>>>(h1, r1, off, cnt, dinv, efin, b1, 1, N);
    agg16w<<<((size_t)N * 64 + 255) / 256, 256, 0, stream>>>(r1, a2, off, cnt, dinv, efin, (const float*)nullptr, 0, N);

    out_ls<<<(N + 3) / 4, 256, 0, stream>>>(a2, W2, b2, out, N);
}

// Round 3
// 615.566 us; speedup vs baseline: 1.8859x; 1.2474x over previous
//
#include <hip/hip_runtime.h>

typedef __attribute__((ext_vector_type(8))) short short8;
typedef __attribute__((ext_vector_type(4))) float floatx4;

#define CHUNK 8192   // edges per binning block
#define SHIFT 8      // nodes per bucket = 256
#define BCAP 12288   // LDS stage cap per bucket (mean 8192, sigma~90 -> 45-sigma margin)

// f32 -> bf16 round-to-nearest-even (inputs are finite; no NaN guard needed)
__device__ __forceinline__ short f2bf(float f) {
    unsigned int u = __float_as_uint(f);
    u = (u + 0x7FFFu + ((u >> 16) & 1u)) >> 16;
    return (short)u;
}

// ---------------- generic exclusive scan (3-pass) ----------------

// per-1024-chunk sums (256 threads x 4 elems)
__global__ void scan_part(const int* __restrict__ cnt, int* __restrict__ bsums, int N) {
    __shared__ int sh[256];
    int tid = threadIdx.x;
    int base = blockIdx.x * 1024 + tid * 4;
    int s = 0;
#pragma unroll
    for (int j = 0; j < 4; ++j) { int idx = base + j; if (idx < N) s += cnt[idx]; }
    sh[tid] = s; __syncthreads();
    for (int d = 128; d > 0; d >>= 1) { if (tid < d) sh[tid] += sh[tid + d]; __syncthreads(); }
    if (tid == 0) bsums[blockIdx.x] = sh[0];
}

// exclusive scan of up to 1024 block sums, single block of 1024 threads
__global__ void scan_small(int* __restrict__ b, int nb) {
    __shared__ int s[1024];
    int tid = threadIdx.x;
    int v = (tid < nb) ? b[tid] : 0;
    s[tid] = v; __syncthreads();
    for (int d = 1; d < 1024; d <<= 1) {
        int t = (tid >= d) ? s[tid - d] : 0;
        __syncthreads();
        s[tid] += t;
        __syncthreads();
    }
    if (tid < nb) b[tid] = s[tid] - v;
}

// apply local scan + block base, in place
__global__ __launch_bounds__(256) void scan_apply(int* __restrict__ v, const int* __restrict__ bsums, int M) {
    __shared__ int sh[256];
    int tid = threadIdx.x;
    int base = blockIdx.x * 1024 + tid * 4;
    int x[4]; int tsum = 0;
#pragma unroll
    for (int j = 0; j < 4; ++j) { int idx = base + j; x[j] = (idx < M) ? v[idx] : 0; tsum += x[j]; }
    sh[tid] = tsum; __syncthreads();
    for (int d = 1; d < 256; d <<= 1) {
        int t = (tid >= d) ? sh[tid - d] : 0;
        __syncthreads();
        sh[tid] += t;
        __syncthreads();
    }
    int run = sh[tid] - tsum + bsums[blockIdx.x];
#pragma unroll
    for (int j = 0; j < 4; ++j) {
        int idx = base + j;
        if (idx < M) { v[idx] = run; run += x[j]; }
    }
}

// ---------------- counting sort of edges by dst ----------------

// pass 1: per-block bucket histogram (bucket = dst>>SHIFT), LDS atomics only.
// ghist layout bucket-major [buk][blk] so the exclusive scan yields deterministic
// per-(bucket,block) bases; bucket base lands at ghist[buk*nblk].
__global__ __launch_bounds__(256) void blockhist(const int* __restrict__ dst, int* __restrict__ ghist,
                                                 int E, int nbuk, int nblk) {
    __shared__ int lh[512];
    int tid = threadIdx.x, blk = blockIdx.x;
    for (int i = tid; i < nbuk; i += 256) lh[i] = 0;
    __syncthreads();
    int base = blk * CHUNK;
    int end = base + CHUNK; if (end > E) end = E;
    for (int i = base + tid; i < end; i += 256)
        atomicAdd(&lh[dst[i] >> SHIFT], 1);
    __syncthreads();
    for (int i = tid; i < nbuk; i += 256) ghist[(size_t)i * nblk + blk] = lh[i];
}

// pass 2: place edges at deterministic (bucket,block) ranges. Payload packed to
// 4B: src in bits [23:0], dst&255 in bits [31:24] (norm is factored out entirely).
__global__ __launch_bounds__(256) void binpass(const int* __restrict__ eidx, const int* __restrict__ ghist,
                                               unsigned* __restrict__ ebin, int E, int nbuk, int nblk) {
    __shared__ int lh[512];
    __shared__ int lb[512];
    int tid = threadIdx.x, blk = blockIdx.x;
    for (int i = tid; i < nbuk; i += 256) { lh[i] = 0; lb[i] = ghist[(size_t)i * nblk + blk]; }
    __syncthreads();
    int base = blk * CHUNK;
    int end = base + CHUNK; if (end > E) end = E;
    for (int i = base + tid; i < end; i += 256) {
        unsigned s = (unsigned)eidx[i];
        unsigned d = (unsigned)eidx[E + i];
        int buk = d >> SHIFT;
        int r = atomicAdd(&lh[buk], 1);
        ebin[lb[buk] + r] = s | ((d & 255u) << 24);
    }
}

// pass 3: one block per bucket (256 nodes). Stage bucket edges in LDS, build the
// per-node histogram (replaces count_deg: zero global atomics), LDS-scan it to
// per-node CSR offsets (replaces the node-level scan chain; writes off/cnt/dinv
// with coalesced stores), then scatter src-only payloads to final CSR slots.
// All writes land in this block's own region -> dense single-XCD writeback.
__global__ __launch_bounds__(256) void permB(const int* __restrict__ ghist, int nblk, int nbuk,
                                             int* __restrict__ off, int* __restrict__ cnt,
                                             float* __restrict__ dinv,
                                             const unsigned* __restrict__ ebin,
                                             unsigned* __restrict__ efin,
                                             int N, int E) {
    __shared__ unsigned stage[BCAP];   // 48 KB
    __shared__ int hist[256];
    __shared__ int sc[256];
    __shared__ int obase[256];
    __shared__ int lcur[256];
    int k = blockIdx.x, tid = threadIdx.x;
    int n0 = k << SHIFT;
    int bstart = ghist[(size_t)k * nblk];
    int bend = (k + 1 < nbuk) ? ghist[(size_t)(k + 1) * nblk] : E;
    int cntb = bend - bstart;
    hist[tid] = 0;
    __syncthreads();
    for (int i = tid; i < cntb; i += 256) {
        unsigned p = ebin[bstart + i];
        if (i < BCAP) stage[i] = p;
        atomicAdd(&hist[p >> 24], 1);
    }
    __syncthreads();
    int h = hist[tid];
    sc[tid] = h; __syncthreads();
    for (int d = 1; d < 256; d <<= 1) {
        int t = (tid >= d) ? sc[tid - d] : 0;
        __syncthreads();
        sc[tid] += t;
        __syncthreads();
    }
    int excl = sc[tid] - h;
    int nn = n0 + tid;
    if (nn < N) {
        off[nn] = bstart + excl;
        cnt[nn] = h;
        dinv[nn] = rsqrtf((float)(h + 1));   // deg includes self-loop
    }
    obase[tid] = bstart + excl;
    lcur[tid] = 0;
    __syncthreads();
    for (int i = tid; i < cntb; i += 256) {
        unsigned p = (i < BCAP) ? stage[i] : ebin[bstart + i];
        int d = p >> 24;
        int r = atomicAdd(&lcur[d], 1);
        efin[obase[d] + r] = p & 0xFFFFFFu;
    }
}

// ---------------- layer 1 GEMM: g1[N,16] = dinv .* (x[N,512] @ W1[512,16]) ----------------
// wave = one 16x16 output tile, mfma_f32_16x16x32_bf16, f32 inputs cvt'd to bf16 in-register.
// Epilogue pre-scales rows by dinv so aggregation needs no per-edge norm.
__global__ __launch_bounds__(256) void gemm1_mfma(const float* __restrict__ x,
                                                  const float* __restrict__ w1,
                                                  const float* __restrict__ dinv,
                                                  float* __restrict__ g1,
                                                  int ntiles, int N) {
    __shared__ __align__(16) float wl[512 * 16];    // 32 KB
    int tid = threadIdx.x;
    for (int i = tid; i < 2048; i += 256)           // 8192 floats = 2048 float4
        ((float4*)wl)[i] = ((const float4*)w1)[i];
    __syncthreads();

    int lane = tid & 63;
    int q = lane >> 4, r = lane & 15;

    // B fragments for all 16 K-iters: lane holds B[k=q*8+j][n=r]
    short8 bf[16];
#pragma unroll
    for (int kk = 0; kk < 16; ++kk) {
        int kb = kk * 32 + q * 8;
        short8 t;
#pragma unroll
        for (int j = 0; j < 8; ++j) t[j] = f2bf(wl[(kb + j) * 16 + r]);
        bf[kk] = t;
    }

    int tile = blockIdx.x * 4 + (tid >> 6);
    if (tile >= ntiles) return;
    int nb = tile * 16;
    int row = nb + r; if (row >= N) row = N - 1;
    const float* xp = x + (size_t)row * 512 + q * 8;   // A[m=r][k=q*8+j]
    floatx4 acc = {0.f, 0.f, 0.f, 0.f};
#pragma unroll
    for (int kk = 0; kk < 16; ++kk) {
        float4 a0 = *(const float4*)(xp + kk * 32);
        float4 a1 = *(const float4*)(xp + kk * 32 + 4);
        short8 af;
        af[0] = f2bf(a0.x); af[1] = f2bf(a0.y); af[2] = f2bf(a0.z); af[3] = f2bf(a0.w);
        af[4] = f2bf(a1.x); af[5] = f2bf(a1.y); af[6] = f2bf(a1.z); af[7] = f2bf(a1.w);
        acc = __builtin_amdgcn_mfma_f32_16x16x32_bf16(af, bf[kk], acc, 0, 0, 0);
    }
    // C/D: col=lane&15, row=(lane>>4)*4+i
#pragma unroll
    for (int i = 0; i < 4; ++i) {
        int rr = nb + q * 4 + i;
        if (rr < N) g1[(size_t)rr * 16 + r] = acc[i] * dinv[rr];
    }
}

// ---------------- CSR aggregate over 16-dim pre-scaled features ----------------
// full wave per node: lane = h (feature, bits 0..3) x j (edge slot, bits 4..5).
// in[] is pre-scaled by dinv (g = dinv.*h), so per-edge work is a pure gather-add:
//   out[n] = dinv[n] * (sum_src g[src] + g[n])  [+bias, relu, *dinv prescale for next layer]
__global__ __launch_bounds__(256) void agg16w(const float* __restrict__ in, float* __restrict__ out,
                                              const int* __restrict__ off, const int* __restrict__ cnt,
                                              const float* __restrict__ dinv,
                                              const unsigned* __restrict__ edges,
                                              const float* __restrict__ bias, int N) {
    int t = blockIdx.x * blockDim.x + threadIdx.x;
    int n = t >> 6;
    if (n >= N) return;
    int lane = t & 63;
    int h = lane & 15, j = lane >> 4;
    int p0 = off[n], c = cnt[n];
    const unsigned* ep = edges + p0;
    float acc = 0.0f;
    for (int i = j; i < c; i += 4) {
        unsigned s = ep[i];
        acc += in[s * 16 + h];
    }
    acc += __shfl_xor(acc, 16, 64);
    acc += __shfl_xor(acc, 32, 64);
    if (j == 0) {
        float di = dinv[n];
        float v = di * (acc + in[n * 16 + h]);
        if (bias) v = fmaxf(v + bias[h], 0.0f) * di;   // layer1: +b1, relu, pre-scale for layer2
        out[n * 16 + h] = v;
    }
}

// ---------------- fused W2 + bias + log_softmax + f32 store ----------------
// one wave per node; lanes 0..39 = classes
__global__ __launch_bounds__(256) void out_ls(const float* __restrict__ a2,
                                              const float* __restrict__ w2,
                                              const float* __restrict__ b2,
                                              float* __restrict__ out, int N) {
    __shared__ float w2s[704];   // 640 used + zero pad so lanes 40..63 read zeros
    __shared__ float b2s[40];
    int tid = threadIdx.x;
    for (int i = tid; i < 704; i += 256) w2s[i] = (i < 640) ? w2[i] : 0.0f;
    if (tid < 40) b2s[tid] = b2[tid];
    __syncthreads();
    int lane = tid & 63;
    int n = blockIdx.x * 4 + (tid >> 6);
    if (n >= N) return;
    const float* ar = a2 + (size_t)n * 16;
    bool act = lane < 40;
    float acc = act ? b2s[lane] : 0.0f;
#pragma unroll
    for (int k = 0; k < 16; ++k) {
        float av = ar[k];                 // wave-uniform broadcast load
        acc += av * w2s[k * 40 + lane];   // zeros for lanes>=40, discarded below
    }
    float v = act ? acc : -__builtin_inff();
#pragma unroll
    for (int s = 32; s > 0; s >>= 1) v = fmaxf(v, __shfl_xor(v, s, 64));
    float ex = act ? expf(acc - v) : 0.0f;
    float ssum = ex;
#pragma unroll
    for (int s = 32; s > 0; s >>= 1) ssum += __shfl_xor(ssum, s, 64);
    float lse = logf(ssum);
    if (act) out[(size_t)n * 40 + lane] = acc - v - lse;
}

// ---------------- launch ----------------

extern "C" void kernel_launch(void* const* d_in, const int* in_sizes, int n_in,
                              void* d_out, int out_size, void* d_ws, size_t ws_size,
                              hipStream_t stream) {
    const float* x   = (const float*)d_in[0];
    const float* W1  = (const float*)d_in[1];
    const float* b1  = (const float*)d_in[2];
    const float* W2  = (const float*)d_in[3];
    const float* b2  = (const float*)d_in[4];
    const int*   eidx = (const int*)d_in[5];
    float* out = (float*)d_out;

    const int N = in_sizes[0] / 512;
    const int E = in_sizes[5] / 2;

    const int NBUK = (N + 255) >> SHIFT;          // buckets of 256 nodes
    const int nblk = (E + CHUNK - 1) / CHUNK;     // binning blocks
    const int M = NBUK * nblk;                    // histogram matrix size

    char* w = (char*)d_ws;
    auto alloc = [&](size_t bytes) { char* p = w; w += (bytes + 255) & ~(size_t)255; return p; };
    int*      off   = (int*)alloc((size_t)N * 4);
    int*      cnt   = (int*)alloc((size_t)N * 4);
    float*    dinv  = (float*)alloc((size_t)N * 4);
    int*      bsums = (int*)alloc(1024 * 4);
    int*      ghist = (int*)alloc((size_t)M * 4);
    unsigned* ebin  = (unsigned*)alloc((size_t)E * 4);
    unsigned* efin  = (unsigned*)alloc((size_t)E * 4);
    // ebin (12.8 MB) is dead after permB; reuse for g1/r1 (6.4 MB each)
    float* g1 = (float*)ebin;
    float* r1 = g1 + (size_t)N * 16;
    float* a2 = g1;   // g1 dead after first agg

    int mb = (M + 1023) / 1024;

    blockhist<<<nblk, 256, 0, stream>>>(eidx + E, ghist, E, NBUK, nblk);
    scan_part<<<mb, 256, 0, stream>>>(ghist, bsums, M);
    scan_small<<<1, 1024, 0, stream>>>(bsums, mb);
    scan_apply<<<mb, 256, 0, stream>>>(ghist, bsums, M);
    binpass<<<nblk, 256, 0, stream>>>(eidx, ghist, ebin, E, NBUK, nblk);
    permB<<<NBUK, 256, 0, stream>>>(ghist, nblk, NBUK, off, cnt, dinv, ebin, efin, N, E);

    int ntiles = (N + 15) / 16;
    gemm1_mfma<<<(ntiles + 3) / 4, 256, 0, stream>>>(x, W1, dinv, g1, ntiles, N);

    agg16w<<<((size_t)N * 64 + 255) / 256, 256, 0, stream>>>(g1, r1, off, cnt, dinv, (const unsigned*)efin, b1, N);
    agg16w<<<((size_t)N * 64 + 255) / 256, 256, 0, stream>>>(r1, a2, off, cnt, dinv, (const unsigned*)efin, (const float*)nullptr, N);

    out_ls<<<(N + 3) / 4, 256, 0, stream>>>(a2, W2, b2, out, N);
}

// Round 4
// 532.351 us; speedup vs baseline: 2.1807x; 1.1563x over previous
//
#include <hip/hip_runtime.h>

typedef __attribute__((ext_vector_type(8))) short short8;
typedef __attribute__((ext_vector_type(4))) float floatx4;

#define CHUNK 8192   // edges per binning block
#define SHIFT 8      // nodes per bucket = 256
#define BCAP 12288   // LDS stage cap per bucket (mean 8192, sigma~90 -> 45-sigma margin)

// f32 -> bf16 round-to-nearest-even (inputs are finite; no NaN guard needed)
__device__ __forceinline__ short f2bf(float f) {
    unsigned int u = __float_as_uint(f);
    u = (u + 0x7FFFu + ((u >> 16) & 1u)) >> 16;
    return (short)u;
}

// ---------------- generic exclusive scan (3-pass) ----------------

__global__ void scan_part(const int* __restrict__ cnt, int* __restrict__ bsums, int N) {
    __shared__ int sh[256];
    int tid = threadIdx.x;
    int base = blockIdx.x * 1024 + tid * 4;
    int s = 0;
#pragma unroll
    for (int j = 0; j < 4; ++j) { int idx = base + j; if (idx < N) s += cnt[idx]; }
    sh[tid] = s; __syncthreads();
    for (int d = 128; d > 0; d >>= 1) { if (tid < d) sh[tid] += sh[tid + d]; __syncthreads(); }
    if (tid == 0) bsums[blockIdx.x] = sh[0];
}

__global__ void scan_small(int* __restrict__ b, int nb) {
    __shared__ int s[1024];
    int tid = threadIdx.x;
    int v = (tid < nb) ? b[tid] : 0;
    s[tid] = v; __syncthreads();
    for (int d = 1; d < 1024; d <<= 1) {
        int t = (tid >= d) ? s[tid - d] : 0;
        __syncthreads();
        s[tid] += t;
        __syncthreads();
    }
    if (tid < nb) b[tid] = s[tid] - v;
}

__global__ __launch_bounds__(256) void scan_apply(int* __restrict__ v, const int* __restrict__ bsums, int M) {
    __shared__ int sh[256];
    int tid = threadIdx.x;
    int base = blockIdx.x * 1024 + tid * 4;
    int x[4]; int tsum = 0;
#pragma unroll
    for (int j = 0; j < 4; ++j) { int idx = base + j; x[j] = (idx < M) ? v[idx] : 0; tsum += x[j]; }
    sh[tid] = tsum; __syncthreads();
    for (int d = 1; d < 256; d <<= 1) {
        int t = (tid >= d) ? sh[tid - d] : 0;
        __syncthreads();
        sh[tid] += t;
        __syncthreads();
    }
    int run = sh[tid] - tsum + bsums[blockIdx.x];
#pragma unroll
    for (int j = 0; j < 4; ++j) {
        int idx = base + j;
        if (idx < M) { v[idx] = run; run += x[j]; }
    }
}

// ---------------- counting sort of edges by dst ----------------

// pass 1: per-block bucket histogram (bucket = dst>>SHIFT), LDS atomics only.
__global__ __launch_bounds__(256) void blockhist(const int* __restrict__ dst, int* __restrict__ ghist,
                                                 int E, int nbuk, int nblk) {
    __shared__ int lh[512];
    int tid = threadIdx.x, blk = blockIdx.x;
    for (int i = tid; i < nbuk; i += 256) lh[i] = 0;
    __syncthreads();
    int base = blk * CHUNK;
    int end = base + CHUNK; if (end > E) end = E;
    for (int i = base + tid; i < end; i += 256)
        atomicAdd(&lh[dst[i] >> SHIFT], 1);
    __syncthreads();
    for (int i = tid; i < nbuk; i += 256) ghist[(size_t)i * nblk + blk] = lh[i];
}

// pass 2: place edges at deterministic (bucket,block) ranges. Payload packed to
// 4B: src in bits [23:0], dst&255 in bits [31:24].
__global__ __launch_bounds__(256) void binpass(const int* __restrict__ eidx, const int* __restrict__ ghist,
                                               unsigned* __restrict__ ebin, int E, int nbuk, int nblk) {
    __shared__ int lh[512];
    __shared__ int lb[512];
    int tid = threadIdx.x, blk = blockIdx.x;
    for (int i = tid; i < nbuk; i += 256) { lh[i] = 0; lb[i] = ghist[(size_t)i * nblk + blk]; }
    __syncthreads();
    int base = blk * CHUNK;
    int end = base + CHUNK; if (end > E) end = E;
    for (int i = base + tid; i < end; i += 256) {
        unsigned s = (unsigned)eidx[i];
        unsigned d = (unsigned)eidx[E + i];
        int buk = d >> SHIFT;
        int r = atomicAdd(&lh[buk], 1);
        ebin[lb[buk] + r] = s | ((d & 255u) << 24);
    }
}

// pass 3: one block per bucket (256 nodes). Builds per-node degrees + CSR offsets
// + dinv in LDS (zero global atomics), then scatters src payloads to final slots.
__global__ __launch_bounds__(256) void permB(const int* __restrict__ ghist, int nblk, int nbuk,
                                             int* __restrict__ off, int* __restrict__ cnt,
                                             float* __restrict__ dinv,
                                             const unsigned* __restrict__ ebin,
                                             unsigned* __restrict__ efin,
                                             int N, int E) {
    __shared__ unsigned stage[BCAP];   // 48 KB
    __shared__ int hist[256];
    __shared__ int sc[256];
    __shared__ int obase[256];
    __shared__ int lcur[256];
    int k = blockIdx.x, tid = threadIdx.x;
    int n0 = k << SHIFT;
    int bstart = ghist[(size_t)k * nblk];
    int bend = (k + 1 < nbuk) ? ghist[(size_t)(k + 1) * nblk] : E;
    int cntb = bend - bstart;
    hist[tid] = 0;
    __syncthreads();
    for (int i = tid; i < cntb; i += 256) {
        unsigned p = ebin[bstart + i];
        if (i < BCAP) stage[i] = p;
        atomicAdd(&hist[p >> 24], 1);
    }
    __syncthreads();
    int h = hist[tid];
    sc[tid] = h; __syncthreads();
    for (int d = 1; d < 256; d <<= 1) {
        int t = (tid >= d) ? sc[tid - d] : 0;
        __syncthreads();
        sc[tid] += t;
        __syncthreads();
    }
    int excl = sc[tid] - h;
    int nn = n0 + tid;
    if (nn < N) {
        off[nn] = bstart + excl;
        cnt[nn] = h;
        dinv[nn] = rsqrtf((float)(h + 1));   // deg includes self-loop
    }
    obase[tid] = bstart + excl;
    lcur[tid] = 0;
    __syncthreads();
    for (int i = tid; i < cntb; i += 256) {
        unsigned p = (i < BCAP) ? stage[i] : ebin[bstart + i];
        int d = p >> 24;
        int r = atomicAdd(&lcur[d], 1);
        efin[obase[d] + r] = p & 0xFFFFFFu;
    }
}

// ---------------- layer 1 GEMM: g1[N,16] = dinv .* (x[N,512] @ W1[512,16]) ----------------
__global__ __launch_bounds__(256) void gemm1_mfma(const float* __restrict__ x,
                                                  const float* __restrict__ w1,
                                                  const float* __restrict__ dinv,
                                                  float* __restrict__ g1,
                                                  int ntiles, int N) {
    __shared__ __align__(16) float wl[512 * 16];    // 32 KB
    int tid = threadIdx.x;
    for (int i = tid; i < 2048; i += 256)
        ((float4*)wl)[i] = ((const float4*)w1)[i];
    __syncthreads();

    int lane = tid & 63;
    int q = lane >> 4, r = lane & 15;

    short8 bf[16];
#pragma unroll
    for (int kk = 0; kk < 16; ++kk) {
        int kb = kk * 32 + q * 8;
        short8 t;
#pragma unroll
        for (int j = 0; j < 8; ++j) t[j] = f2bf(wl[(kb + j) * 16 + r]);
        bf[kk] = t;
    }

    int tile = blockIdx.x * 4 + (tid >> 6);
    if (tile >= ntiles) return;
    int nb = tile * 16;
    int row = nb + r; if (row >= N) row = N - 1;
    const float* xp = x + (size_t)row * 512 + q * 8;
    floatx4 acc = {0.f, 0.f, 0.f, 0.f};
#pragma unroll
    for (int kk = 0; kk < 16; ++kk) {
        float4 a0 = *(const float4*)(xp + kk * 32);
        float4 a1 = *(const float4*)(xp + kk * 32 + 4);
        short8 af;
        af[0] = f2bf(a0.x); af[1] = f2bf(a0.y); af[2] = f2bf(a0.z); af[3] = f2bf(a0.w);
        af[4] = f2bf(a1.x); af[5] = f2bf(a1.y); af[6] = f2bf(a1.z); af[7] = f2bf(a1.w);
        acc = __builtin_amdgcn_mfma_f32_16x16x32_bf16(af, bf[kk], acc, 0, 0, 0);
    }
#pragma unroll
    for (int i = 0; i < 4; ++i) {
        int rr = nb + q * 4 + i;
        if (rr < N) g1[(size_t)rr * 16 + r] = acc[i] * dinv[rr];
    }
}

// ---------------- CSR aggregate, float4-gather layout ----------------
// wave per node; lane = j (edge slot, bits 5..2) x h4 (float4 slice, bits 1..0).
// One wave-instruction gathers 16 edges' float4 slices (16 lines) vs 4 before:
// 4x fewer dependent gather rounds per node. Butterfly-reduce over j leaves the
// full sum in every lane.
__device__ __forceinline__ float4 shfl_xor4(float4 v, int d) {
    float4 r;
    r.x = __shfl_xor(v.x, d, 64);
    r.y = __shfl_xor(v.y, d, 64);
    r.z = __shfl_xor(v.z, d, 64);
    r.w = __shfl_xor(v.w, d, 64);
    return r;
}
__device__ __forceinline__ float4 add4(float4 a, float4 b) {
    return make_float4(a.x + b.x, a.y + b.y, a.z + b.z, a.w + b.w);
}

// layer-1 agg: out = dinv .* relu(dinv*(sum g[src] + g[n]) + b1)  (pre-scaled for layer 2)
__global__ __launch_bounds__(256) void agg16w(const float* __restrict__ in, float* __restrict__ out,
                                              const int* __restrict__ off, const int* __restrict__ cnt,
                                              const float* __restrict__ dinv,
                                              const unsigned* __restrict__ edges,
                                              const float* __restrict__ bias, int N) {
    int t = blockIdx.x * blockDim.x + threadIdx.x;
    int n = t >> 6;
    if (n >= N) return;
    int lane = t & 63;
    int h4 = lane & 3, j = lane >> 2;
    int p0 = off[n], c = cnt[n];
    const unsigned* ep = edges + p0;
    float4 acc = make_float4(0.f, 0.f, 0.f, 0.f);
    for (int i = j; i < c; i += 16) {
        unsigned s = ep[i];
        acc = add4(acc, *(const float4*)(in + (size_t)s * 16 + h4 * 4));
    }
#pragma unroll
    for (int d = 4; d < 64; d <<= 1) acc = add4(acc, shfl_xor4(acc, d));
    if (j == 0) {
        float di = dinv[n];
        float4 sv = *(const float4*)(in + (size_t)n * 16 + h4 * 4);
        float4 b4 = *(const float4*)(bias + h4 * 4);
        float4 v;
        v.x = fmaxf(di * (acc.x + sv.x) + b4.x, 0.f) * di;
        v.y = fmaxf(di * (acc.y + sv.y) + b4.y, 0.f) * di;
        v.z = fmaxf(di * (acc.z + sv.z) + b4.z, 0.f) * di;
        v.w = fmaxf(di * (acc.w + sv.w) + b4.w, 0.f) * di;
        *(float4*)(out + (size_t)n * 16 + h4 * 4) = v;
    }
}

// ---------------- fused layer-2 agg + W2 + bias + log_softmax ----------------
// wave per node: float4-gather agg (as above), then broadcast the 16 a2 values
// via readlane-shuffles and run the 40-class dot + softmax in the same wave.
__global__ __launch_bounds__(256) void agg_out(const float* __restrict__ in,
                                               const int* __restrict__ off, const int* __restrict__ cnt,
                                               const float* __restrict__ dinv,
                                               const unsigned* __restrict__ edges,
                                               const float* __restrict__ w2,
                                               const float* __restrict__ b2,
                                               float* __restrict__ out, int N) {
    __shared__ float w2s[704];   // 640 used + zero pad so lanes 40..63 read zeros
    __shared__ float b2s[40];
    int tid = threadIdx.x;
    for (int i = tid; i < 704; i += 256) w2s[i] = (i < 640) ? w2[i] : 0.0f;
    if (tid < 40) b2s[tid] = b2[tid];
    __syncthreads();

    int n = blockIdx.x * 4 + (tid >> 6);
    if (n >= N) return;
    int lane = tid & 63;
    int h4 = lane & 3, j = lane >> 2;
    int p0 = off[n], c = cnt[n];
    const unsigned* ep = edges + p0;
    float4 acc = make_float4(0.f, 0.f, 0.f, 0.f);
    for (int i = j; i < c; i += 16) {
        unsigned s = ep[i];
        acc = add4(acc, *(const float4*)(in + (size_t)s * 16 + h4 * 4));
    }
#pragma unroll
    for (int d = 4; d < 64; d <<= 1) acc = add4(acc, shfl_xor4(acc, d));
    // every lane now holds the full sum for its h4 slice
    float di = dinv[n];
    float4 sv = *(const float4*)(in + (size_t)n * 16 + h4 * 4);
    float4 v4;
    v4.x = di * (acc.x + sv.x);
    v4.y = di * (acc.y + sv.y);
    v4.z = di * (acc.z + sv.z);
    v4.w = di * (acc.w + sv.w);

    // broadcast a2[0..15]: a2[k] lives in component k&3 of lanes with h4 == k>>2
    float a2k[16];
#pragma unroll
    for (int k = 0; k < 16; ++k) {
        float comp = (k & 3) == 0 ? v4.x : (k & 3) == 1 ? v4.y : (k & 3) == 2 ? v4.z : v4.w;
        a2k[k] = __shfl(comp, k >> 2, 64);
    }

    bool act = lane < 40;
    float dot = act ? b2s[lane] : 0.0f;
#pragma unroll
    for (int k = 0; k < 16; ++k)
        dot += a2k[k] * w2s[k * 40 + lane];   // zeros for lanes>=40

    float v = act ? dot : -__builtin_inff();
#pragma unroll
    for (int s = 32; s > 0; s >>= 1) v = fmaxf(v, __shfl_xor(v, s, 64));
    float ex = act ? expf(dot - v) : 0.0f;
    float ssum = ex;
#pragma unroll
    for (int s = 32; s > 0; s >>= 1) ssum += __shfl_xor(ssum, s, 64);
    float lse = logf(ssum);
    if (act) out[(size_t)n * 40 + lane] = dot - v - lse;
}

// ---------------- launch ----------------

extern "C" void kernel_launch(void* const* d_in, const int* in_sizes, int n_in,
                              void* d_out, int out_size, void* d_ws, size_t ws_size,
                              hipStream_t stream) {
    const float* x   = (const float*)d_in[0];
    const float* W1  = (const float*)d_in[1];
    const float* b1  = (const float*)d_in[2];
    const float* W2  = (const float*)d_in[3];
    const float* b2  = (const float*)d_in[4];
    const int*   eidx = (const int*)d_in[5];
    float* out = (float*)d_out;

    const int N = in_sizes[0] / 512;
    const int E = in_sizes[5] / 2;

    const int NBUK = (N + 255) >> SHIFT;
    const int nblk = (E + CHUNK - 1) / CHUNK;
    const int M = NBUK * nblk;

    char* w = (char*)d_ws;
    auto alloc = [&](size_t bytes) { char* p = w; w += (bytes + 255) & ~(size_t)255; return p; };
    int*      off   = (int*)alloc((size_t)N * 4);
    int*      cnt   = (int*)alloc((size_t)N * 4);
    float*    dinv  = (float*)alloc((size_t)N * 4);
    int*      bsums = (int*)alloc(1024 * 4);
    int*      ghist = (int*)alloc((size_t)M * 4);
    unsigned* ebin  = (unsigned*)alloc((size_t)E * 4);
    unsigned* efin  = (unsigned*)alloc((size_t)E * 4);
    // ebin (12.8 MB) is dead after permB; reuse for g1/r1 (6.4 MB each)
    float* g1 = (float*)ebin;
    float* r1 = g1 + (size_t)N * 16;

    int mb = (M + 1023) / 1024;

    blockhist<<<nblk, 256, 0, stream>>>(eidx + E, ghist, E, NBUK, nblk);
    scan_part<<<mb, 256, 0, stream>>>(ghist, bsums, M);
    scan_small<<<1, 1024, 0, stream>>>(bsums, mb);
    scan_apply<<<mb, 256, 0, stream>>>(ghist, bsums, M);
    binpass<<<nblk, 256, 0, stream>>>(eidx, ghist, ebin, E, NBUK, nblk);
    permB<<<NBUK, 256, 0, stream>>>(ghist, nblk, NBUK, off, cnt, dinv, ebin, efin, N, E);

    int ntiles = (N + 15) / 16;
    gemm1_mfma<<<(ntiles + 3) / 4, 256, 0, stream>>>(x, W1, dinv, g1, ntiles, N);

    agg16w<<<((size_t)N * 64 + 255) / 256, 256, 0, stream>>>(g1, r1, off, cnt, dinv, (const unsigned*)efin, b1, N);
    agg_out<<<(N + 3) / 4, 256, 0, stream>>>(r1, off, cnt, dinv, (const unsigned*)efin, W2, b2, out, N);
}